// Round 2
// baseline (5721.450 us; speedup 1.0000x reference)
//
#include <hip/hip_runtime.h>
#include <hip/hip_bf16.h>
#include <math.h>

#define NH 128
#define NH3 384
#define NR 20

__device__ __forceinline__ float silu_f(float x) { return x / (1.0f + expf(-x)); }

// ---------------------------------------------------------------- init s = emb[z]
__global__ __launch_bounds__(256) void k_init_s(const int* __restrict__ z,
                                                const float* __restrict__ emb,
                                                float* __restrict__ s, int total4) {
    int idx = blockIdx.x * 256 + threadIdx.x;
    if (idx < total4) {
        int n = idx >> 5, c4 = idx & 31;
        ((float4*)s)[idx] = ((const float4*)emb)[(size_t)z[n] * 32 + c4];
    }
}

// ---------------------------------------------------------------- mf = silu(s@W1+b1)@W2+b2
__global__ __launch_bounds__(256, 4) void k_mf(const float* __restrict__ s,
                                               const float* __restrict__ W1,
                                               const float* __restrict__ b1,
                                               const float* __restrict__ W2,
                                               const float* __restrict__ b2,
                                               float* __restrict__ mf) {
    __shared__ float s_t[16 * 128];
    __shared__ float h_t[16 * 128];
    const int tid = threadIdx.x;
    const size_t nb = (size_t)blockIdx.x * 16;
    {
        const float4* p = (const float4*)(s + nb * 128);
        ((float4*)s_t)[tid] = p[tid];
        ((float4*)s_t)[tid + 256] = p[tid + 256];
    }
    __syncthreads();
    const int c0 = tid & 63;
    const int ty = tid >> 6;   // 4 groups of 4 nodes
    // phase A: h = silu(s@W1 + b1)
    {
        float acc[4][2];
        float bb0 = b1[c0], bb1 = b1[c0 + 64];
        #pragma unroll
        for (int i = 0; i < 4; i++) { acc[i][0] = bb0; acc[i][1] = bb1; }
        for (int k = 0; k < 128; k += 4) {
            float4 sv[4];
            #pragma unroll
            for (int i = 0; i < 4; i++) sv[i] = *(const float4*)&s_t[(ty * 4 + i) * 128 + k];
            #pragma unroll
            for (int kk = 0; kk < 4; kk++) {
                float w0 = W1[(size_t)(k + kk) * 128 + c0];
                float w1 = W1[(size_t)(k + kk) * 128 + c0 + 64];
                #pragma unroll
                for (int i = 0; i < 4; i++) {
                    float a = (&sv[i].x)[kk];
                    acc[i][0] = fmaf(a, w0, acc[i][0]);
                    acc[i][1] = fmaf(a, w1, acc[i][1]);
                }
            }
        }
        #pragma unroll
        for (int i = 0; i < 4; i++) {
            h_t[(ty * 4 + i) * 128 + c0] = silu_f(acc[i][0]);
            h_t[(ty * 4 + i) * 128 + c0 + 64] = silu_f(acc[i][1]);
        }
    }
    __syncthreads();
    // phase B: mf = h@W2 + b2
    {
        float acc[4][6];
        #pragma unroll
        for (int q = 0; q < 6; q++) {
            float bb = b2[c0 + 64 * q];
            #pragma unroll
            for (int i = 0; i < 4; i++) acc[i][q] = bb;
        }
        for (int k = 0; k < 128; k += 4) {
            float4 hv[4];
            #pragma unroll
            for (int i = 0; i < 4; i++) hv[i] = *(const float4*)&h_t[(ty * 4 + i) * 128 + k];
            #pragma unroll
            for (int kk = 0; kk < 4; kk++) {
                float w[6];
                #pragma unroll
                for (int q = 0; q < 6; q++) w[q] = W2[(size_t)(k + kk) * 384 + c0 + 64 * q];
                #pragma unroll
                for (int i = 0; i < 4; i++) {
                    float a = (&hv[i].x)[kk];
                    #pragma unroll
                    for (int q = 0; q < 6; q++) acc[i][q] = fmaf(a, w[q], acc[i][q]);
                }
            }
        }
        #pragma unroll
        for (int i = 0; i < 4; i++)
            #pragma unroll
            for (int q = 0; q < 6; q++)
                mf[(nb + ty * 4 + i) * 384 + c0 + 64 * q] = acc[i][q];
    }
}

// ---------------------------------------------------------------- edge message pass
// 64 edges per block (512 thr). Phase1: lane=edge, j wave-uniform -> scalar weight loads.
// Phase2: lane=column -> coalesced gathers + atomics. wf staged in LDS in two j-halves.
// w_s accumulates DIRECTLY into s (s is not read by this kernel).
__global__ __launch_bounds__(512, 4) void k_edge(const int* __restrict__ ei,
                                                 const float* __restrict__ edist,
                                                 const float* __restrict__ evec,
                                                 const float* __restrict__ mf,
                                                 const float* __restrict__ v,
                                                 const float* __restrict__ Wr,   // 20x384
                                                 const float* __restrict__ br,   // 384
                                                 float* __restrict__ sAcc,
                                                 float* __restrict__ dV,
                                                 int nE) {
    __shared__ float wfl[192 * 65];
    __shared__ float rbl[20 * 64];
    const int tid = threadIdx.x;
    const int lane = tid & 63;
    const int wv = tid >> 6;  // 0..7
    const int e0 = blockIdx.x * 64;
    const float inv_sqrt3 = 0.57735026918962576451f;

    // distributed rbf compute
    {
        float dd = edist[e0 + lane];
        float t = 0.62831853071795864769f * dd;  // pi*d/5
        float cosc = (dd <= 5.0f) ? (0.5f * (cosf(t) + 1.0f)) : 0.0f;
        float ic = cosc / dd;
        for (int rr = wv; rr < 20; rr += 8)
            rbl[rr * 64 + lane] = sinf((float)(rr + 1) * t) * ic;
    }
    __syncthreads();
    float rb[20];
    #pragma unroll
    for (int r = 0; r < 20; ++r) rb[r] = rbl[r * 64 + lane];

    // phase 1a: wf for j in [0,192)
    for (int jj = 0; jj < 24; ++jj) {
        int j = __builtin_amdgcn_readfirstlane(wv * 24 + jj);
        float acc = br[j];
        #pragma unroll
        for (int r = 0; r < 20; ++r) acc = fmaf(rb[r], Wr[r * 384 + j], acc);
        wfl[j * 65 + lane] = acc;
    }
    __syncthreads();

    // phase 2a: w_s atomics (into s) + stash w_vs lower half
    int srcs[8], dsts[8];
    float wvs0[8];
    #pragma unroll
    for (int i = 0; i < 8; ++i) {
        int el = wv * 8 + i;
        int e = __builtin_amdgcn_readfirstlane(e0 + el);
        int sn = ei[e], dn = ei[nE + e];
        srcs[i] = sn; dsts[i] = dn;
        const float* mfr = mf + (size_t)sn * 384;
        float p0 = wfl[lane * 65 + el] * mfr[lane];
        float p1 = wfl[(64 + lane) * 65 + el] * mfr[64 + lane];
        wvs0[i] = wfl[(128 + lane) * 65 + el] * mfr[128 + lane];
        atomicAdd(sAcc + (size_t)dn * 128 + lane, p0);
        atomicAdd(sAcc + (size_t)dn * 128 + 64 + lane, p1);
    }
    __syncthreads();

    // phase 1b: wf for j in [192,384)
    for (int jj = 0; jj < 24; ++jj) {
        int j = __builtin_amdgcn_readfirstlane(192 + wv * 24 + jj);
        float acc = br[j];
        #pragma unroll
        for (int r = 0; r < 20; ++r) acc = fmaf(rb[r], Wr[r * 384 + j], acc);
        wfl[(j - 192) * 65 + lane] = acc;
    }
    __syncthreads();

    // phase 2b: w_vs upper half, w_vv, v gather, dv atomics
    #pragma unroll
    for (int i = 0; i < 8; ++i) {
        int el = wv * 8 + i;
        int e = __builtin_amdgcn_readfirstlane(e0 + el);
        int sn = srcs[i], dn = dsts[i];
        float ex = evec[3 * e], ey = evec[3 * e + 1], ez = evec[3 * e + 2];
        float inv_n = 1.0f / sqrtf(ex * ex + ey * ey + ez * ez);
        float un[3] = { ex * inv_n, ey * inv_n, ez * inv_n };
        const float* mfr = mf + (size_t)sn * 384;
        float wvs1 = wfl[lane * 65 + el] * mfr[192 + lane];         // j=192+lane
        float wvv0 = wfl[(64 + lane) * 65 + el] * mfr[256 + lane];  // j=256+lane
        float wvv1 = wfl[(128 + lane) * 65 + el] * mfr[320 + lane]; // j=320+lane
        const float* vr = v + (size_t)sn * 384;
        float* dvr = dV + (size_t)dn * 384;
        #pragma unroll
        for (int hh = 0; hh < 2; ++hh) {
            int h = hh * 64 + lane;
            float a = (hh ? wvs1 : wvs0[i]) * inv_sqrt3;
            float b = (hh ? wvv1 : wvv0);
            #pragma unroll
            for (int d = 0; d < 3; ++d) {
                float val = fmaf(vr[d * 128 + h], a, b * un[d]);
                atomicAdd(dvr + d * 128 + h, val);
            }
        }
    }
}

// ---------------------------------------------------------------- node update
// s already holds s+ds (edge kernel accumulated in place).
__global__ __launch_bounds__(256, 2) void k_upd(float* __restrict__ s,
                                                float* __restrict__ v,
                                                float* __restrict__ dV,
                                                const float* __restrict__ Wv,  // 128x256
                                                const float* __restrict__ W1,  // 256x128
                                                const float* __restrict__ b1,
                                                const float* __restrict__ W2,  // 128x384
                                                const float* __restrict__ b2) {
    __shared__ float sv[8 * 128];
    __shared__ float vn[8 * 384];
    __shared__ float vvb[8 * 768];
    __shared__ float ft[8 * 256];
    __shared__ float u1[8 * 128];
    __shared__ float vd[8 * 128];
    const int tid = threadIdx.x;
    const size_t nb = (size_t)blockIdx.x * 8;
    const float inv_sqrtH = 0.08838834764831845f;
    const float inv_sqrt2 = 0.70710678118654752440f;

    // phase 0: load s (already summed); v_new = v + dv*invsqrtH ; re-zero dv
    {
        ((float4*)sv)[tid] = ((const float4*)(s + nb * 128))[tid];
        float4* v4 = (float4*)(v + nb * 384);
        float4* e4 = (float4*)(dV + nb * 384);
        #pragma unroll
        for (int t = 0; t < 3; ++t) {
            float4 av = v4[tid + 256 * t], bv = e4[tid + 256 * t];
            ((float4*)vn)[tid + 256 * t] =
                make_float4(fmaf(bv.x, inv_sqrtH, av.x), fmaf(bv.y, inv_sqrtH, av.y),
                            fmaf(bv.z, inv_sqrtH, av.z), fmaf(bv.w, inv_sqrtH, av.w));
            e4[tid + 256 * t] = make_float4(0.f, 0.f, 0.f, 0.f);
        }
    }
    __syncthreads();
    const int c0 = tid & 63;
    const int ty = tid >> 6;
    // phase 1: vv = v_new @ Wv
    {
        float acc[2][3][4];
        #pragma unroll
        for (int i = 0; i < 2; i++)
            #pragma unroll
            for (int d = 0; d < 3; d++)
                #pragma unroll
                for (int cc = 0; cc < 4; cc++) acc[i][d][cc] = 0.f;
        for (int k = 0; k < 128; k += 4) {
            float4 av[2][3];
            #pragma unroll
            for (int i = 0; i < 2; i++)
                #pragma unroll
                for (int d = 0; d < 3; d++)
                    av[i][d] = *(const float4*)&vn[(ty * 2 + i) * 384 + d * 128 + k];
            #pragma unroll
            for (int kk = 0; kk < 4; kk++) {
                float wc[4];
                #pragma unroll
                for (int cc = 0; cc < 4; cc++) wc[cc] = Wv[(size_t)(k + kk) * 256 + c0 + 64 * cc];
                #pragma unroll
                for (int i = 0; i < 2; i++)
                    #pragma unroll
                    for (int d = 0; d < 3; d++) {
                        float a = (&av[i][d].x)[kk];
                        #pragma unroll
                        for (int cc = 0; cc < 4; cc++)
                            acc[i][d][cc] = fmaf(a, wc[cc], acc[i][d][cc]);
                    }
            }
        }
        #pragma unroll
        for (int i = 0; i < 2; i++)
            #pragma unroll
            for (int d = 0; d < 3; d++)
                #pragma unroll
                for (int cc = 0; cc < 4; cc++)
                    vvb[(ty * 2 + i) * 768 + d * 256 + c0 + 64 * cc] = acc[i][d][cc];
    }
    __syncthreads();
    // phase 2: v_dot, v_norm, feat
    {
        int h = tid & 127, g = tid >> 7;
        #pragma unroll
        for (int t = 0; t < 4; ++t) {
            int i = g * 4 + t;
            float v1x = vvb[i * 768 + h], v1y = vvb[i * 768 + 256 + h], v1z = vvb[i * 768 + 512 + h];
            float v2x = vvb[i * 768 + 128 + h], v2y = vvb[i * 768 + 384 + h], v2z = vvb[i * 768 + 640 + h];
            vd[i * 128 + h] = (v1x * v2x + v1y * v2y + v1z * v2z) * inv_sqrtH;
            ft[i * 256 + h] = sv[i * 128 + h];
            ft[i * 256 + 128 + h] = sqrtf(v2x * v2x + v2y * v2y + v2z * v2z + 1e-12f);
        }
    }
    __syncthreads();
    // phase 3: u1 = silu(feat @ W1 + b1)
    {
        float acc[2][2];
        float bb0 = b1[c0], bb1 = b1[c0 + 64];
        #pragma unroll
        for (int i = 0; i < 2; i++) { acc[i][0] = bb0; acc[i][1] = bb1; }
        for (int k = 0; k < 256; k += 4) {
            float4 f[2];
            #pragma unroll
            for (int i = 0; i < 2; i++) f[i] = *(const float4*)&ft[(ty * 2 + i) * 256 + k];
            #pragma unroll
            for (int kk = 0; kk < 4; kk++) {
                float w0 = W1[(size_t)(k + kk) * 128 + c0];
                float w1 = W1[(size_t)(k + kk) * 128 + c0 + 64];
                #pragma unroll
                for (int i = 0; i < 2; i++) {
                    float a = (&f[i].x)[kk];
                    acc[i][0] = fmaf(a, w0, acc[i][0]);
                    acc[i][1] = fmaf(a, w1, acc[i][1]);
                }
            }
        }
        #pragma unroll
        for (int i = 0; i < 2; i++) {
            u1[(ty * 2 + i) * 128 + c0] = silu_f(acc[i][0]);
            u1[(ty * 2 + i) * 128 + c0 + 64] = silu_f(acc[i][1]);
        }
    }
    __syncthreads();
    // phase 4: uf = u1 @ W2 + b2 + final gated updates
    {
        float acc[2][6];
        #pragma unroll
        for (int q = 0; q < 6; q++) {
            float bb = b2[c0 + 64 * q];
            #pragma unroll
            for (int i = 0; i < 2; i++) acc[i][q] = bb;
        }
        for (int k = 0; k < 128; k += 4) {
            float4 uu[2];
            #pragma unroll
            for (int i = 0; i < 2; i++) uu[i] = *(const float4*)&u1[(ty * 2 + i) * 128 + k];
            #pragma unroll
            for (int kk = 0; kk < 4; kk++) {
                float w[6];
                #pragma unroll
                for (int q = 0; q < 6; q++) w[q] = W2[(size_t)(k + kk) * 384 + c0 + 64 * q];
                #pragma unroll
                for (int i = 0; i < 2; i++) {
                    float a = (&uu[i].x)[kk];
                    #pragma unroll
                    for (int q = 0; q < 6; q++) acc[i][q] = fmaf(a, w[q], acc[i][q]);
                }
            }
        }
        #pragma unroll
        for (int i = 0; i < 2; i++) {
            int node = ty * 2 + i;
            size_t nr = nb + node;
            #pragma unroll
            for (int hh = 0; hh < 2; ++hh) {
                int h = c0 + 64 * hh;
                float a_ss = acc[i][hh], a_sv = acc[i][2 + hh], a_v = acc[i][4 + hh];
                s[nr * 128 + h] = sv[node * 128 + h] + (vd[node * 128 + h] * a_sv + a_ss) * inv_sqrt2;
                #pragma unroll
                for (int d = 0; d < 3; ++d)
                    v[nr * 384 + d * 128 + h] =
                        vn[node * 384 + d * 128 + h] + vvb[node * 768 + d * 256 + h] * a_v;
            }
        }
    }
}

// ---------------------------------------------------------------- output head + mean
__global__ __launch_bounds__(256, 4) void k_out(const float* __restrict__ s,
                                                const float* __restrict__ ow1,  // 128x64
                                                const float* __restrict__ ob1,
                                                const float* __restrict__ ow2,  // 64x1
                                                const float* __restrict__ ob2,
                                                float* __restrict__ out, int nNodes) {
    __shared__ float st[16 * 128];
    __shared__ float red[4];
    const int tid = threadIdx.x;
    const size_t nb = (size_t)blockIdx.x * 16;
    {
        const float4* p = (const float4*)(s + nb * 128);
        ((float4*)st)[tid] = p[tid];
        ((float4*)st)[tid + 256] = p[tid + 256];
    }
    __syncthreads();
    const int c = tid & 63;
    const int ty = tid >> 6;
    float acc[4];
    float bb = ob1[c];
    #pragma unroll
    for (int i = 0; i < 4; i++) acc[i] = bb;
    for (int k = 0; k < 128; k += 4) {
        float4 sv[4];
        #pragma unroll
        for (int i = 0; i < 4; i++) sv[i] = *(const float4*)&st[(ty * 4 + i) * 128 + k];
        #pragma unroll
        for (int kk = 0; kk < 4; kk++) {
            float w = ow1[(size_t)(k + kk) * 64 + c];
            #pragma unroll
            for (int i = 0; i < 4; i++) acc[i] = fmaf((&sv[i].x)[kk], w, acc[i]);
        }
    }
    float w2 = ow2[c];
    float p = 0.f;
    #pragma unroll
    for (int i = 0; i < 4; i++) p += silu_f(acc[i]) * w2;
    #pragma unroll
    for (int off = 32; off > 0; off >>= 1) p += __shfl_down(p, off, 64);
    if (c == 0) red[ty] = p;
    __syncthreads();
    if (tid == 0) {
        float val = (red[0] + red[1] + red[2] + red[3]) * (1.0f / (float)nNodes);
        if (blockIdx.x == 0) val += ob2[0];
        atomicAdd(out, val);
    }
}

// ----------------------------------------------------------------
extern "C" void kernel_launch(void* const* d_in, const int* in_sizes, int n_in,
                              void* d_out, int out_size, void* d_ws, size_t ws_size,
                              hipStream_t stream) {
    const int*   z     = (const int*)d_in[0];
    const int*   ei    = (const int*)d_in[1];
    const float* edist = (const float*)d_in[2];
    const float* evec  = (const float*)d_in[3];
    const float* emb   = (const float*)d_in[4];
    const float* mw1   = (const float*)d_in[5];
    const float* mb1   = (const float*)d_in[6];
    const float* mw2   = (const float*)d_in[7];
    const float* mb2   = (const float*)d_in[8];
    const float* rw    = (const float*)d_in[9];
    const float* rbb   = (const float*)d_in[10];
    const float* uvw   = (const float*)d_in[11];
    const float* uw1   = (const float*)d_in[12];
    const float* ub1   = (const float*)d_in[13];
    const float* uw2   = (const float*)d_in[14];
    const float* ub2   = (const float*)d_in[15];
    const float* ow1   = (const float*)d_in[16];
    const float* ob1   = (const float*)d_in[17];
    const float* ow2   = (const float*)d_in[18];
    const float* ob2   = (const float*)d_in[19];

    const int N = in_sizes[0];
    const int E = in_sizes[2];

    // workspace layout (floats): s | v | mf | dv = N*1280 floats (244.1 MiB)
    const size_t need = (size_t)N * 1280 * sizeof(float);
    hipMemsetAsync(d_out, 0, out_size * sizeof(float), stream);
    if (ws_size < need) return;  // diagnostic: clean absmax==|ref| failure, not a fault

    float* ws = (float*)d_ws;
    float* s  = ws;
    float* v  = s + (size_t)N * 128;
    float* mf = v + (size_t)N * 384;
    float* dV = mf + (size_t)N * 384;

    hipMemsetAsync(v, 0, (size_t)N * 384 * sizeof(float), stream);
    hipMemsetAsync(dV, 0, (size_t)N * 384 * sizeof(float), stream);

    k_init_s<<<(N * 32 + 255) / 256, 256, 0, stream>>>(z, emb, s, N * 32);

    for (int l = 0; l < 3; ++l) {
        k_mf<<<N / 16, 256, 0, stream>>>(s, mw1 + (size_t)l * 16384, mb1 + l * 128,
                                         mw2 + (size_t)l * 49152, mb2 + l * 384, mf);
        k_edge<<<E / 64, 512, 0, stream>>>(ei, edist, evec, mf, v,
                                           rw + (size_t)l * 7680, rbb + l * 384, s, dV, E);
        k_upd<<<N / 8, 256, 0, stream>>>(s, v, dV, uvw + (size_t)l * 32768,
                                         uw1 + (size_t)l * 32768, ub1 + l * 128,
                                         uw2 + (size_t)l * 49152, ub2 + l * 384);
    }
    k_out<<<N / 16, 256, 0, stream>>>(s, ow1, ob1, ow2, ob2, (float*)d_out, N);
}